// Round 6
// baseline (55540.216 us; speedup 1.0000x reference)
//
#include <hip/hip_runtime.h>
#include <hip/hip_bf16.h>
#include <hip/hip_fp16.h>
#include <math.h>

// ---------------------------------------------------------------------------
// OfficialXLSTMModel: B=4, S=2048, D=1024, L=4, H=4, DH=256, K=4, UP=1344
// Input dtype (fp32 vs bf16) detected AT RUNTIME from ln1_w's bit pattern.
// Internal compute fp32; residual X fp32; canonical activations bf16.
// Workspace: exactly 128 MiB.
// R10: MFMA recurrence. R9 post-mortem: per-thread v_dot2 chains kept the
//     VALU pipe as the floor (~54% busy on active CUs, ~4100 cy/step/SIMD);
//     partitioning reads differently couldn't fix an instruction-count bound.
//     New k_recur: block = head (grid 4!), 1024 thr = 16 waves. The matvec
//     y[1024] = W[1024x256] h[256] batched over B=4 becomes an M=4 (b),
//     N=1024, K=256 GEMM per step on mfma_f32_16x16x32_f16:
//       - W^T fragments (B operand) are LOOP-INVARIANT: 32 f16x8 frags/wave
//         (4 n-tiles x 8 k-tiles) = 128 regs; the whole 512KB weight matrix
//         is register-resident per CU. Zero weight memory traffic in loop.
//       - A operand = H batch: b replicated into rows via lane&3; 8
//         ds_read_b128/wave/step from 544B-strided LDS replicas.
//       - C: rows 0..3 = b live in lanes<16 as f32x4 -> 8 ds_write_b64 to
//         ylds (40B stride, conflict-free writes, 4-way reads).
//       - update: all 1024 threads own one (b,cell): 4 LDS reads + fast
//         transcendentals + f16 h write; GN stays deferred in k_gn.
//     VALU/step/thread ~520 -> ~50 instr; MFMA issue ~614 cy/SIMD/step.
// R9: k_gn deferred GroupNorm (kept). R8: f16 state + fast transcendentals.
// ---------------------------------------------------------------------------

typedef unsigned int  u32;
typedef unsigned short u16;
typedef __hip_bfloat16 bf16;

typedef short bf16x8 __attribute__((ext_vector_type(8)));   // 8 bf16 MFMA A/B frag
typedef _Float16 f16x8 __attribute__((ext_vector_type(8))); // 8 f16 MFMA A/B frag
typedef float f32x4  __attribute__((ext_vector_type(4)));   // MFMA C/D frag
typedef _Float16 half2t __attribute__((ext_vector_type(2)));

#define EPSF 1e-5f
#define SIGF32 0x3F800000u

// ---- helpers --------------------------------------------------------------
__device__ __forceinline__ float bfu2f(u16 u){ return __uint_as_float(((u32)u) << 16); }
__device__ __forceinline__ float ldm(const void* p, long i, int f32){
  return f32 ? ((const float*)p)[i] : bfu2f(((const u16*)p)[i]);
}
__device__ __forceinline__ float f16u2f(u16 u){ return (float)__builtin_bit_cast(_Float16, u); }

// ---- canary: signal environmental mismatch through absmax -----------------
__global__ __launch_bounds__(256) void k_canary(const u32* __restrict__ sig,
                                                void* __restrict__ out, int n, float code){
  int f32 = (sig[0] == SIGF32);
  int i = blockIdx.x*256 + threadIdx.x;
  if (i >= n) return;
  float v = (i == 0) ? code : 0.f;
  if (f32) ((float*)out)[i] = v;
  else     ((bf16*)out)[i]  = __float2bfloat16(v);
}

// ---- cast x -> residual X fp32 --------------------------------------------
__global__ __launch_bounds__(256) void k_cast(const void* __restrict__ in,
                                              const u32* __restrict__ sig,
                                              float* __restrict__ out){
  int f32 = (sig[0] == SIGF32);
  long i = (long)blockIdx.x*256 + threadIdx.x;    // < 2097152 (x4 elements)
  if (f32){
    ((float4*)out)[i] = ((const float4*)in)[i];
  } else {
    ushort4 v = ((const ushort4*)in)[i];
    float4 f;
    f.x = bfu2f(v.x); f.y = bfu2f(v.y); f.z = bfu2f(v.z); f.w = bfu2f(v.w);
    ((float4*)out)[i] = f;
  }
}

// ---- generic elementwise convert -> canonical bf16 ------------------------
__global__ __launch_bounds__(256) void k_cvt(const void* __restrict__ src, long off,
                                             const u32* __restrict__ sig,
                                             bf16* __restrict__ dst, int n){
  int f32 = (sig[0] == SIGF32);
  int i = blockIdx.x*256 + threadIdx.x;
  if (i < n) dst[i] = __float2bfloat16(ldm(src, off + i, f32));
}

// ---- LayerNorm over D=1024, fp32 in -> bf16 (or dtype-matched final) out --
__global__ __launch_bounds__(256) void k_ln(const float* __restrict__ X,
                                            const void* __restrict__ w, long woff,
                                            const u32* __restrict__ sig,
                                            void* __restrict__ out, int outf){
  int f32 = (sig[0] == SIGF32);
  int row = blockIdx.x, t = threadIdx.x;
  float4 xv = ((const float4*)(X + (long)row*1024))[t];
  float s1 = xv.x + xv.y + xv.z + xv.w;
  float s2 = xv.x*xv.x + xv.y*xv.y + xv.z*xv.z + xv.w*xv.w;
  #pragma unroll
  for (int off = 32; off >= 1; off >>= 1){ s1 += __shfl_xor(s1, off); s2 += __shfl_xor(s2, off); }
  __shared__ float rb[8];
  if ((t & 63) == 0){ rb[t>>6] = s1; rb[4 + (t>>6)] = s2; }
  __syncthreads();
  s1 = rb[0]+rb[1]+rb[2]+rb[3];
  s2 = rb[4]+rb[5]+rb[6]+rb[7];
  float mu  = s1 * (1.f/1024.f);
  float var = s2 * (1.f/1024.f) - mu*mu;
  float rs  = rsqrtf(fmaxf(var, 0.f) + EPSF);
  float xs[4] = {xv.x, xv.y, xv.z, xv.w};
  #pragma unroll
  for (int j = 0; j < 4; j++){
    float val = (xs[j]-mu)*rs*ldm(w, woff + t*4 + j, f32);
    long oi = (long)row*1024 + t*4 + j;
    if (outf && f32) ((float*)out)[oi] = val;
    else             ((bf16*)out)[oi]  = __float2bfloat16(val);
  }
}

// ---- causal depthwise conv (K=4) + SiLU: XN -> WX z/o column region -------
__global__ __launch_bounds__(256) void k_conv(const bf16* __restrict__ XN,
                                              const void* __restrict__ cw, long cwoff,
                                              const void* __restrict__ cb, long cboff,
                                              const u32* __restrict__ sig,
                                              bf16* __restrict__ WX){
  int f32 = (sig[0] == SIGF32);
  int idx = blockIdx.x*256 + threadIdx.x;        // < 8388608
  int c = idx & 1023;
  int s = (idx >> 10) & 2047;
  int b = idx >> 21;
  float acc = ldm(cb, cboff + c, f32);
  const bf16* xp = XN + idx;
  #pragma unroll
  for (int k = 0; k < 4; k++){
    int sk = s - 3 + k;
    float xv = (sk >= 0) ? (float)xp[(k-3)*1024] : 0.f;
    acc += xv * ldm(cw, cwoff + c*4 + k, f32);
  }
  float sg = 1.f / (1.f + __expf(-acc));
  WX[(long)b*8388608 + (long)(c>>8)*2097152 + (long)s*1024 + 512 + (c & 255)]
      = __float2bfloat16(acc * sg);
}

// ---- pack rker into MFMA B-operand fragments (f16) ------------------------
// wbuf layout (uint4 granularity): [(h*16 + w)*32 + kt*4 + j][64 lane].
// Fragment (h, wave w, k-tile kt, n-tile j): lane l holds
//   W^T[k = kt*32 + (l>>4)*8 + i][n = (w*4+j)*16 + (l&15)]  for i = 0..7,
// where W[n = g*256+cell][k = d] = rker[h][d][g][cell], f16.
// Each u32 output = f16 pair (k even, k odd); ip = i/2 selects the pair.
__global__ __launch_bounds__(256) void k_packrk(const void* __restrict__ rk, long off,
                                                const u32* __restrict__ sig,
                                                u32* __restrict__ wbuf){
  int f32 = (sig[0] == SIGF32);
  int idx = blockIdx.x*256 + threadIdx.x;        // < 524288
  if (idx >= 524288) return;
  int ip   = idx & 3;
  int lane = (idx >> 2) & 63;
  int j    = (idx >> 8) & 3;
  int kt   = (idx >> 10) & 7;
  int w    = (idx >> 13) & 15;
  int h    = idx >> 17;
  int n  = (w*4 + j)*16 + (lane & 15);
  int k0 = kt*32 + ((lane >> 4) & 3)*8 + ip*2;
  int g = n >> 8, cell = n & 255;
  long p = off + (long)h*262144 + (long)k0*1024 + g*256 + cell;
  float a = ldm(rk, p, f32);
  float b = ldm(rk, p + 1024, f32);
  u32 lo = (u32)__builtin_bit_cast(u16, (_Float16)a);
  u32 hi = (u32)__builtin_bit_cast(u16, (_Float16)b);
  wbuf[idx] = lo | (hi << 16);
}

// ---- tiled transpose: in[R][C] (fp32/bf16) -> out[C][R] bf16 --------------
__global__ __launch_bounds__(256) void k_transpose(const void* __restrict__ in, long off,
                                                   const u32* __restrict__ sig,
                                                   bf16* __restrict__ out, int R, int C){
  int f32 = (sig[0] == SIGF32);
  __shared__ bf16 tile[32][33];
  int tx = threadIdx.x & 31, ty = threadIdx.x >> 5;
  int r0 = blockIdx.y*32, c0 = blockIdx.x*32;
  #pragma unroll
  for (int i = 0; i < 4; i++)
    tile[ty + i*8][tx] = __float2bfloat16(ldm(in, off + (long)(r0 + ty + i*8)*C + c0 + tx, f32));
  __syncthreads();
  #pragma unroll
  for (int i = 0; i < 4; i++) out[(long)(c0 + ty + i*8)*R + r0 + tx] = tile[tx][ty + i*8];
}

// ---- bf16 MFMA GEMM, 128x128 tile, direct global loads --------------------
__global__ __launch_bounds__(256) void k_gemm(const bf16* __restrict__ A, int lda, int aoff, int agate,
                                              const bf16* __restrict__ B0,
                                              const bf16* __restrict__ B1, int ldb, int nsplit,
                                              int K, int mode,
                                              bf16* __restrict__ outb, int ldo, int woff,
                                              float* __restrict__ resid){
  int lane = threadIdx.x & 63, wv = threadIdx.x >> 6;
  int wrow = wv >> 1, wcol = wv & 1;
  int m15 = lane & 15, q = lane >> 4;
  int mBase = blockIdx.x*128 + wrow*64;
  int nBase = blockIdx.y*128 + wcol*64;

  const bf16* Ap[4]; const bf16* Bp[4];
  #pragma unroll
  for (int i = 0; i < 4; i++){
    int row = mBase + i*16 + m15;
    long abase = agate ? ((long)(row >> 11)*8388608 + (long)(row & 2047)*1024)
                       : ((long)row*lda);
    Ap[i] = A + abase + aoff + q*8;
    int n = nBase + i*16 + m15;
    const bf16* bb = (n < nsplit) ? (B0 + (long)n*ldb) : (B1 + (long)(n - nsplit)*ldb);
    Bp[i] = bb + q*8;
  }
  f32x4 acc[4][4];
  f32x4 zero = {0.f, 0.f, 0.f, 0.f};
  #pragma unroll
  for (int i = 0; i < 4; i++)
    #pragma unroll
    for (int j = 0; j < 4; j++) acc[i][j] = zero;

  for (int k0 = 0; k0 < K; k0 += 32){
    bf16x8 af[4], bfg[4];
    #pragma unroll
    for (int i = 0; i < 4; i++){ af[i]  = *reinterpret_cast<const bf16x8*>(Ap[i]); Ap[i] += 32; }
    #pragma unroll
    for (int i = 0; i < 4; i++){ bfg[i] = *reinterpret_cast<const bf16x8*>(Bp[i]); Bp[i] += 32; }
    #pragma unroll
    for (int i = 0; i < 4; i++)
      #pragma unroll
      for (int j = 0; j < 4; j++)
        acc[i][j] = __builtin_amdgcn_mfma_f32_16x16x32_bf16(af[i], bfg[j], acc[i][j], 0, 0, 0);
  }

  #pragma unroll
  for (int i = 0; i < 4; i++){
    #pragma unroll
    for (int j = 0; j < 4; j++){
      #pragma unroll
      for (int r = 0; r < 4; r++){
        int row = mBase + i*16 + q*4 + r;       // C/D layout: col=lane&15, row=quad*4+reg
        int col = nBase + j*16 + m15;
        float v = acc[i][j][r];
        if (mode == 0){
          outb[(long)row*ldo + col] = __float2bfloat16(v);
        } else if (mode == 1){
          outb[(long)(row >> 11)*8388608 + (long)(row & 2047)*1024 + woff + col] = __float2bfloat16(v);
        } else {
          resid[(long)row*1024 + col] += v;
        }
      }
    }
  }
}

// ---- GEGLU activation: U[8192][2688] -> E[8192][1344] ---------------------
__global__ __launch_bounds__(256) void k_act(const bf16* __restrict__ U, bf16* __restrict__ E){
  int idx = blockIdx.x*256 + threadIdx.x;        // < 8192*1344
  int row = idx / 1344;
  int j   = idx - row*1344;
  float g = (float)U[(long)row*2688 + j];
  float v = (float)U[(long)row*2688 + 1344 + j];
  float ge = 0.5f * g * (1.f + erff(g * 0.70710678118654752f));
  E[idx] = __float2bfloat16(ge * v);
}

// ---- sLSTM recurrence via register-resident MFMA (GN deferred to k_gn) ----
// grid = 4 (one block per head h); 1024 threads = 16 waves.
// Wave w owns n-tiles (w*4+j)*16, j=0..3, full K=256: 32 loop-invariant
// W^T fragments in registers. Per step:
//   A-frag (H batch, b = row&3 replication): 8 ds_read_b128 from 544B-strided
//   LDS replicas; 32 mfma_f32_16x16x32_f16 (4 independent chains of 8);
//   lanes<16 hold y[b=reg r][n=tile+lane] -> 2 ds_write_b64 per tile to ylds
//   (40B stride). B1. Update: thread (b=tid>>8, cell=tid&255) reads its 4
//   gates, cell update (fast transcendentals), writes f16 h to replica b and
//   hn to the dead WX gate-i column. B2.
__global__ __launch_bounds__(1024, 4) void k_recur(bf16* __restrict__ WX,        // [4b][4h][2048][1024]
                                                const uint4* __restrict__ wbufq, // fragments (see k_packrk)
                                                const void* __restrict__ cb, long cboff,
                                                const u32*  __restrict__ sig,
                                                int szero){
  int f32 = (sig[0] == SIGF32);
  int h = blockIdx.x;
  int tid = threadIdx.x;
  int lane = tid & 63, w = tid >> 6;
  int b = tid >> 8, cell = tid & 255;

  // loop-invariant weight fragments: 32 x f16x8 = 128 regs
  f16x8 wfr[32];
  {
    const uint4* src = wbufq + (long)(h*16 + w)*32*64 + lane;
    #pragma unroll
    for (int f = 0; f < 32; f++){
      uint4 v = src[f*64];
      wfr[f] = __builtin_bit_cast(f16x8, v);
    }
  }
  #pragma unroll
  for (int f = 0; f < 32; f++) asm volatile("" : "+v"(wfr[f]));

  __shared__ __align__(16) u16 hsr[4*272];        // 4 b-replicas, 544B stride
  __shared__ __align__(16) char ylds[1024*40];    // [n]: 4 b f32 at byte n*40 + b*4
  if (tid < 544) ((u32*)hsr)[tid] = 0u;

  float bs0 = ldm(cb, cboff + h*1024 +   0 + cell, f32);
  float bs1 = ldm(cb, cboff + h*1024 + 256 + cell, f32);
  float bs2 = ldm(cb, cboff + h*1024 + 512 + cell, f32);
  float bs3 = ldm(cb, cboff + h*1024 + 768 + cell, f32);

  const u16* wxu = (const u16*)WX + ((long)b*4 + h)*2097152 + cell;
  u16* yout = (u16*)WX + ((long)b*4 + h)*2097152 + cell;

  const char* hbase = (const char*)hsr + (lane & 3)*544 + ((lane >> 4) & 3)*16;
  char* ybase = ylds + ((long)w*64 + lane)*40;              // lanes<16 only
  const char* yrd = ylds + (long)cell*40 + b*4;

  float c = 0.f, n = 0.f, m = 0.f;
  u16 wx0 = wxu[0], wx1 = wxu[256], wx2 = wxu[512], wx3 = wxu[768];
  __syncthreads();

  for (int s = 0; s < 2048; s++){
    const u16* wxn = wxu + ((s < 2047) ? 1024 : 0);
    u16 nx0 = wxn[0], nx1 = wxn[256], nx2 = wxn[512], nx3 = wxn[768];
    int off = s * szero;                         // runtime 0

    f16x8 af[8];
    #pragma unroll
    for (int kt = 0; kt < 8; kt++)
      af[kt] = *(const f16x8*)(hbase + kt*64 + off);

    f32x4 c0 = {0,0,0,0}, c1 = {0,0,0,0}, c2 = {0,0,0,0}, c3 = {0,0,0,0};
    #pragma unroll
    for (int kt = 0; kt < 8; kt++){
      c0 = __builtin_amdgcn_mfma_f32_16x16x32_f16(af[kt], wfr[kt*4+0], c0, 0, 0, 0);
      c1 = __builtin_amdgcn_mfma_f32_16x16x32_f16(af[kt], wfr[kt*4+1], c1, 0, 0, 0);
      c2 = __builtin_amdgcn_mfma_f32_16x16x32_f16(af[kt], wfr[kt*4+2], c2, 0, 0, 0);
      c3 = __builtin_amdgcn_mfma_f32_16x16x32_f16(af[kt], wfr[kt*4+3], c3, 0, 0, 0);
    }
    if (lane < 16){                              // rows 0..3 = b in regs r
      *(float2*)(ybase +    0) = make_float2(c0[0], c0[1]);
      *(float2*)(ybase +    8) = make_float2(c0[2], c0[3]);
      *(float2*)(ybase +  640) = make_float2(c1[0], c1[1]);
      *(float2*)(ybase +  648) = make_float2(c1[2], c1[3]);
      *(float2*)(ybase + 1280) = make_float2(c2[0], c2[1]);
      *(float2*)(ybase + 1288) = make_float2(c2[2], c2[3]);
      *(float2*)(ybase + 1920) = make_float2(c3[0], c3[1]);
      *(float2*)(ybase + 1928) = make_float2(c3[2], c3[3]);
    }
    __syncthreads();                             // B1: ylds ready

    float a0 = *(const float*)(yrd +     0 + off) + bs0 + bfu2f(wx0);
    float a1 = *(const float*)(yrd + 10240)       + bs1 + bfu2f(wx1);
    float a2 = *(const float*)(yrd + 20480)       + bs2 + bfu2f(wx2);
    float a3 = *(const float*)(yrd + 30720)       + bs3 + bfu2f(wx3);

    float e1   = __expf(-fabsf(a1));
    float lsig = fminf(a1, 0.f) - __logf(1.f + e1);
    float lfm  = m + lsig;
    float mn   = fmaxf(a0, lfm);
    float ig   = __expf(a0 - mn);
    float fg   = __expf(lfm - mn);
    float t2   = __expf(-2.f*fabsf(a2));
    float th   = __builtin_copysignf(__fdividef(1.f - t2, 1.f + t2), a2);
    float cn   = fg*c + ig*th;
    float nn   = fg*n + ig;
    float sg   = __fdividef(1.f, 1.f + __expf(-a3));
    float hn   = sg * __fdividef(cn, nn);
    c = cn; n = nn; m = mn;
    u16 h16 = __builtin_bit_cast(u16, (_Float16)hn);
    hsr[b*272 + cell] = h16;
    yout[(long)s*1024] = h16;                    // f16 hn for deferred GN
    __syncthreads();                             // B2: hsr(s+1) visible

    wxu += 1024;
    wx0 = nx0; wx1 = nx1; wx2 = nx2; wx3 = nx3;
  }
}

// ---- deferred GroupNorm + residual add: one block per (bh, s) row ---------
__global__ __launch_bounds__(256) void k_gn(const u16* __restrict__ Y,   // [16][2048][1024] rows, col<256 used
                                            const void* __restrict__ gnw, long gnoff,
                                            const u32* __restrict__ sig,
                                            float* __restrict__ X){
  int f32 = (sig[0] == SIGF32);
  int r = blockIdx.x;                 // < 32768
  int bh = r >> 11, s = r & 2047, b = bh >> 2, h = bh & 3;
  int t = threadIdx.x;                // cell
  float y = f16u2f(Y[(long)bh*2097152 + (long)s*1024 + t]);
  float s1 = y, s2 = y*y;
  #pragma unroll
  for (int off = 32; off >= 1; off >>= 1){ s1 += __shfl_xor(s1, off); s2 += __shfl_xor(s2, off); }
  __shared__ float rb[8];
  if ((t & 63) == 0){ rb[t>>6] = s1; rb[4 + (t>>6)] = s2; }
  __syncthreads();
  s1 = rb[0]+rb[1]+rb[2]+rb[3];
  s2 = rb[4]+rb[5]+rb[6]+rb[7];
  float mu  = s1 * (1.f/256.f);
  float var = s2 * (1.f/256.f) - mu*mu;
  float rs  = rsqrtf(fmaxf(var, 0.f) + EPSF);
  float gw  = ldm(gnw, gnoff + h*256 + t, f32);
  X[(long)b*2097152 + (long)s*1024 + h*256 + t] += (y - mu)*rs*gw;
}

// ---------------------------------------------------------------------------
extern "C" void kernel_launch(void* const* d_in, const int* in_sizes, int n_in,
                              void* d_out, int out_size, void* d_ws, size_t ws_size,
                              hipStream_t stream){
  const void* x_in   = d_in[0];
  const void* ln1_w  = d_in[1];
  const void* conv_w = d_in[2];
  const void* conv_b = d_in[3];
  const void* wi     = d_in[4];
  const void* wf     = d_in[5];
  const void* wz     = d_in[6];
  const void* wo     = d_in[7];
  const void* rker   = d_in[8];
  const void* cell_b = d_in[9];
  const void* gn_w   = d_in[10];
  const void* ln2_w  = d_in[11];
  const void* ff_up  = d_in[12];
  const void* ff_dn  = d_in[13];
  const void* post_w = d_in[14];
  const u32* sig = (const u32*)ln1_w;

  if (ws_size < 134217728ULL){
    k_canary<<<(out_size+255)/256, 256, 0, stream>>>(sig, d_out, out_size, 4000.f);
    return;
  }
  if (n_in < 15 || in_sizes[0] != 8388608 || in_sizes[8] != 4194304 ||
      in_sizes[12] != 11010048 || out_size != 8388608){
    k_canary<<<(out_size+255)/256, 256, 0, stream>>>(sig, d_out, out_size, 8000.f);
    return;
  }

  char* ws = (char*)d_ws;
  // layout (exactly 128 MiB):
  //   [0,32M)    X    fp32 residual
  //   [32,48M)   XN   bf16 LN output
  //   [48,64M)   scratch: wbuf 2M | gW 2M | fupT 5.25M | fdnT 2.63M
  //   [64,128M)  WX bf16 [4 b][4 h][2048 s][1024]; conv output lives in its
  //              z/o cols until side-1 gemms; recur's hn (f16) overwrites the
  //              dead gate-i cols; U(44M)+E(21M) alias it in FFN.
  float* X    = (float*)(ws + 0);
  bf16*  XN   = (bf16*) (ws + 33554432);
  u32*   wbuf = (u32*)  (ws + 50331648);
  bf16*  gW   = (bf16*) (ws + 50331648 + 2097152);
  bf16*  fupT = (bf16*) (ws + 50331648 + 4194304);
  bf16*  fdnT = (bf16*) (ws + 50331648 + 9699328);
  bf16*  WX   = (bf16*) (ws + 67108864);
  bf16*  U    = WX;
  bf16*  E    = (bf16*) (ws + 67108864 + 44040192);

  k_cast<<<8192, 256, 0, stream>>>(x_in, sig, X);

  for (int l = 0; l < 4; l++){
    k_ln<<<8192, 256, 0, stream>>>(X, ln1_w, (long)l*1024, sig, XN, 0);
    k_conv<<<32768, 256, 0, stream>>>(XN, conv_w, (long)l*4096, conv_b, (long)l*1024, sig, WX);

    // canonical bf16 gate weights for this layer
    k_cvt<<<1024, 256, 0, stream>>>(wi, (long)l*262144, sig, gW +      0, 262144);
    k_cvt<<<1024, 256, 0, stream>>>(wf, (long)l*262144, sig, gW + 262144, 262144);
    k_cvt<<<1024, 256, 0, stream>>>(wz, (long)l*262144, sig, gW + 524288, 262144);
    k_cvt<<<1024, 256, 0, stream>>>(wo, (long)l*262144, sig, gW + 786432, 262144);

    for (int h = 0; h < 4; h++){
      // gates i,f: A = conv output (in WX z/o cols), writes i/f cols
      k_gemm<<<dim3(64,4), 256, 0, stream>>>(WX, 0, h*2097152 + 512, 1,
          gW + h*65536, gW + 262144 + h*65536, 256, 256,
          256, 1, WX, 0, h*2097152 + 0, nullptr);
    }
    k_packrk<<<2048, 256, 0, stream>>>(rker, (long)l*1048576, sig, wbuf);
    for (int h = 0; h < 4; h++){
      // gates z,o: A = pre-conv XN, overwrites z/o cols (conv data now dead)
      k_gemm<<<dim3(64,4), 256, 0, stream>>>(XN, 1024, h*256, 0,
          gW + 524288 + h*65536, gW + 786432 + h*65536, 256, 256,
          256, 1, WX, 0, h*2097152 + 512, nullptr);
    }

    k_recur<<<4, 1024, 0, stream>>>(WX, (const uint4*)wbuf,
                                    cell_b, (long)l*4096, sig, 0);
    k_gn<<<32768, 256, 0, stream>>>((const u16*)WX, gn_w, (long)l*1024, sig, X);

    k_ln<<<8192, 256, 0, stream>>>(X, ln2_w, (long)l*1024, sig, XN, 0);
    k_transpose<<<dim3(84,32), 256, 0, stream>>>(ff_up, (long)l*2752512, sig, fupT, 1024, 2688);
    k_gemm<<<dim3(64,21), 256, 0, stream>>>(XN, 1024, 0, 0, fupT, fupT, 1024, 1<<30,
        1024, 0, U, 2688, 0, nullptr);
    k_act<<<43008, 256, 0, stream>>>(U, E);
    k_transpose<<<dim3(32,42), 256, 0, stream>>>(ff_dn, (long)l*1376256, sig, fdnT, 1344, 1024);
    k_gemm<<<dim3(64,8), 256, 0, stream>>>(E, 1344, 0, 0, fdnT, fdnT, 1344, 1<<30,
        1344, 2, nullptr, 0, 0, X);
  }

  k_ln<<<8192, 256, 0, stream>>>(X, post_w, 0, sig, d_out, 1);
}

// Round 8
// 30821.100 us; speedup vs baseline: 1.8020x; 1.8020x over previous
//
#include <hip/hip_runtime.h>
#include <hip/hip_bf16.h>
#include <hip/hip_fp16.h>
#include <math.h>

// ---------------------------------------------------------------------------
// OfficialXLSTMModel: B=4, S=2048, D=1024, L=4, H=4, DH=256, K=4, UP=1344
// Input dtype (fp32 vs bf16) detected AT RUNTIME from ln1_w's bit pattern.
// Internal compute fp32; residual X fp32; canonical activations bf16.
// Workspace: exactly 128 MiB.
// R12: minimal-diff MFMA recurrence. R11 (8-wave + WX interleave + conv->STG,
//     all at once) failed correctness; bug not localizable by inspection.
//     This round: everything EXCEPT k_recur reverts to R10 verbatim (R10
//     passed on HW -> its packrk/wbuf layout, hsr replica A-operand, 40B ylds,
//     update math, yout->WX, k_gn(WX) are all hardware-verified). k_recur is
//     R10's code restructured to 8 waves (512 thr, launch_bounds(512,2) ->
//     256-reg unified budget; R10's 16-wave/128-reg version could not hold
//     512KB of weights by arithmetic). Wave w owns n-tiles w*8+j8, mapped to
//     R10's UNCHANGED wbuf via w'=2w+(j8>>2), j'=j8&3 (uint4 index identity:
//     32768h + 2048w' + 256kt + 64j' + lane). kt 0..4 register-resident
//     (40 frags = 160 VGPR = 320KB/CU); kt 5..7 streamed from L2 per step
//     (24 uint4/lane ~= 192KB/step/CU, pipelined in 3 groups of 8).
//     Update phase: R10's per-(b,cell) code, two b's per thread (b0, b0+2).
// R10: M=4 MFMA 16x16x32_f16 recurrence structure (verified correct on HW).
// R9: k_gn deferred GroupNorm. R8: f16 state + fast transcendentals.
// ---------------------------------------------------------------------------

typedef unsigned int  u32;
typedef unsigned short u16;
typedef __hip_bfloat16 bf16;

typedef short bf16x8 __attribute__((ext_vector_type(8)));   // 8 bf16 MFMA A/B frag
typedef _Float16 f16x8 __attribute__((ext_vector_type(8))); // 8 f16 MFMA A/B frag
typedef float f32x4  __attribute__((ext_vector_type(4)));   // MFMA C/D frag

#define EPSF 1e-5f
#define SIGF32 0x3F800000u

// ---- helpers --------------------------------------------------------------
__device__ __forceinline__ float bfu2f(u16 u){ return __uint_as_float(((u32)u) << 16); }
__device__ __forceinline__ float ldm(const void* p, long i, int f32){
  return f32 ? ((const float*)p)[i] : bfu2f(((const u16*)p)[i]);
}
__device__ __forceinline__ float f16u2f(u16 u){ return (float)__builtin_bit_cast(_Float16, u); }

// ---- canary: signal environmental mismatch through absmax -----------------
__global__ __launch_bounds__(256) void k_canary(const u32* __restrict__ sig,
                                                void* __restrict__ out, int n, float code){
  int f32 = (sig[0] == SIGF32);
  int i = blockIdx.x*256 + threadIdx.x;
  if (i >= n) return;
  float v = (i == 0) ? code : 0.f;
  if (f32) ((float*)out)[i] = v;
  else     ((bf16*)out)[i]  = __float2bfloat16(v);
}

// ---- cast x -> residual X fp32 --------------------------------------------
__global__ __launch_bounds__(256) void k_cast(const void* __restrict__ in,
                                              const u32* __restrict__ sig,
                                              float* __restrict__ out){
  int f32 = (sig[0] == SIGF32);
  long i = (long)blockIdx.x*256 + threadIdx.x;    // < 2097152 (x4 elements)
  if (f32){
    ((float4*)out)[i] = ((const float4*)in)[i];
  } else {
    ushort4 v = ((const ushort4*)in)[i];
    float4 f;
    f.x = bfu2f(v.x); f.y = bfu2f(v.y); f.z = bfu2f(v.z); f.w = bfu2f(v.w);
    ((float4*)out)[i] = f;
  }
}

// ---- generic elementwise convert -> canonical bf16 ------------------------
__global__ __launch_bounds__(256) void k_cvt(const void* __restrict__ src, long off,
                                             const u32* __restrict__ sig,
                                             bf16* __restrict__ dst, int n){
  int f32 = (sig[0] == SIGF32);
  int i = blockIdx.x*256 + threadIdx.x;
  if (i < n) dst[i] = __float2bfloat16(ldm(src, off + i, f32));
}

// ---- LayerNorm over D=1024, fp32 in -> bf16 (or dtype-matched final) out --
__global__ __launch_bounds__(256) void k_ln(const float* __restrict__ X,
                                            const void* __restrict__ w, long woff,
                                            const u32* __restrict__ sig,
                                            void* __restrict__ out, int outf){
  int f32 = (sig[0] == SIGF32);
  int row = blockIdx.x, t = threadIdx.x;
  float4 xv = ((const float4*)(X + (long)row*1024))[t];
  float s1 = xv.x + xv.y + xv.z + xv.w;
  float s2 = xv.x*xv.x + xv.y*xv.y + xv.z*xv.z + xv.w*xv.w;
  #pragma unroll
  for (int off = 32; off >= 1; off >>= 1){ s1 += __shfl_xor(s1, off); s2 += __shfl_xor(s2, off); }
  __shared__ float rb[8];
  if ((t & 63) == 0){ rb[t>>6] = s1; rb[4 + (t>>6)] = s2; }
  __syncthreads();
  s1 = rb[0]+rb[1]+rb[2]+rb[3];
  s2 = rb[4]+rb[5]+rb[6]+rb[7];
  float mu  = s1 * (1.f/1024.f);
  float var = s2 * (1.f/1024.f) - mu*mu;
  float rs  = rsqrtf(fmaxf(var, 0.f) + EPSF);
  float xs[4] = {xv.x, xv.y, xv.z, xv.w};
  #pragma unroll
  for (int j = 0; j < 4; j++){
    float val = (xs[j]-mu)*rs*ldm(w, woff + t*4 + j, f32);
    long oi = (long)row*1024 + t*4 + j;
    if (outf && f32) ((float*)out)[oi] = val;
    else             ((bf16*)out)[oi]  = __float2bfloat16(val);
  }
}

// ---- causal depthwise conv (K=4) + SiLU: XN -> WX z/o column region -------
__global__ __launch_bounds__(256) void k_conv(const bf16* __restrict__ XN,
                                              const void* __restrict__ cw, long cwoff,
                                              const void* __restrict__ cb, long cboff,
                                              const u32* __restrict__ sig,
                                              bf16* __restrict__ WX){
  int f32 = (sig[0] == SIGF32);
  int idx = blockIdx.x*256 + threadIdx.x;        // < 8388608
  int c = idx & 1023;
  int s = (idx >> 10) & 2047;
  int b = idx >> 21;
  float acc = ldm(cb, cboff + c, f32);
  const bf16* xp = XN + idx;
  #pragma unroll
  for (int k = 0; k < 4; k++){
    int sk = s - 3 + k;
    float xv = (sk >= 0) ? (float)xp[(k-3)*1024] : 0.f;
    acc += xv * ldm(cw, cwoff + c*4 + k, f32);
  }
  float sg = 1.f / (1.f + __expf(-acc));
  WX[(long)b*8388608 + (long)(c>>8)*2097152 + (long)s*1024 + 512 + (c & 255)]
      = __float2bfloat16(acc * sg);
}

// ---- pack rker into MFMA B-operand fragments (f16) — R10 verbatim ---------
// wbuf layout (uint4 granularity): [(h*16 + w')*32 + kt*4 + j'][64 lane].
// Fragment (h, w', kt, j'): lane l holds
//   W^T[k = kt*32 + (l>>4)*8 + i][n = (w'*4+j')*16 + (l&15)]  for i = 0..7,
// where W[n = g*256 + cell][k = d] = rker[h][d][g][cell], f16.
// Each u32 output = f16 pair (k even, k odd); ip = i/2 selects the pair.
__global__ __launch_bounds__(256) void k_packrk(const void* __restrict__ rk, long off,
                                                const u32* __restrict__ sig,
                                                u32* __restrict__ wbuf){
  int f32 = (sig[0] == SIGF32);
  int idx = blockIdx.x*256 + threadIdx.x;        // < 524288
  if (idx >= 524288) return;
  int ip   = idx & 3;
  int lane = (idx >> 2) & 63;
  int j    = (idx >> 8) & 3;
  int kt   = (idx >> 10) & 7;
  int w    = (idx >> 13) & 15;
  int h    = idx >> 17;
  int n  = (w*4 + j)*16 + (lane & 15);
  int k0 = kt*32 + ((lane >> 4) & 3)*8 + ip*2;
  int g = n >> 8, cell = n & 255;
  long p = off + (long)h*262144 + (long)k0*1024 + g*256 + cell;
  float a = ldm(rk, p, f32);
  float b = ldm(rk, p + 1024, f32);
  u32 lo = (u32)__builtin_bit_cast(u16, (_Float16)a);
  u32 hi = (u32)__builtin_bit_cast(u16, (_Float16)b);
  wbuf[idx] = lo | (hi << 16);
}

// ---- tiled transpose: in[R][C] (fp32/bf16) -> out[C][R] bf16 --------------
__global__ __launch_bounds__(256) void k_transpose(const void* __restrict__ in, long off,
                                                   const u32* __restrict__ sig,
                                                   bf16* __restrict__ out, int R, int C){
  int f32 = (sig[0] == SIGF32);
  __shared__ bf16 tile[32][33];
  int tx = threadIdx.x & 31, ty = threadIdx.x >> 5;
  int r0 = blockIdx.y*32, c0 = blockIdx.x*32;
  #pragma unroll
  for (int i = 0; i < 4; i++)
    tile[ty + i*8][tx] = __float2bfloat16(ldm(in, off + (long)(r0 + ty + i*8)*C + c0 + tx, f32));
  __syncthreads();
  #pragma unroll
  for (int i = 0; i < 4; i++) out[(long)(c0 + ty + i*8)*R + r0 + tx] = tile[tx][ty + i*8];
}

// ---- bf16 MFMA GEMM, 128x128 tile, direct global loads — R10 verbatim -----
__global__ __launch_bounds__(256) void k_gemm(const bf16* __restrict__ A, int lda, int aoff, int agate,
                                              const bf16* __restrict__ B0,
                                              const bf16* __restrict__ B1, int ldb, int nsplit,
                                              int K, int mode,
                                              bf16* __restrict__ outb, int ldo, int woff,
                                              float* __restrict__ resid){
  int lane = threadIdx.x & 63, wv = threadIdx.x >> 6;
  int wrow = wv >> 1, wcol = wv & 1;
  int m15 = lane & 15, q = lane >> 4;
  int mBase = blockIdx.x*128 + wrow*64;
  int nBase = blockIdx.y*128 + wcol*64;

  const bf16* Ap[4]; const bf16* Bp[4];
  #pragma unroll
  for (int i = 0; i < 4; i++){
    int row = mBase + i*16 + m15;
    long abase = agate ? ((long)(row >> 11)*8388608 + (long)(row & 2047)*1024)
                       : ((long)row*lda);
    Ap[i] = A + abase + aoff + q*8;
    int n = nBase + i*16 + m15;
    const bf16* bb = (n < nsplit) ? (B0 + (long)n*ldb) : (B1 + (long)(n - nsplit)*ldb);
    Bp[i] = bb + q*8;
  }
  f32x4 acc[4][4];
  f32x4 zero = {0.f, 0.f, 0.f, 0.f};
  #pragma unroll
  for (int i = 0; i < 4; i++)
    #pragma unroll
    for (int j = 0; j < 4; j++) acc[i][j] = zero;

  for (int k0 = 0; k0 < K; k0 += 32){
    bf16x8 af[4], bfg[4];
    #pragma unroll
    for (int i = 0; i < 4; i++){ af[i]  = *reinterpret_cast<const bf16x8*>(Ap[i]); Ap[i] += 32; }
    #pragma unroll
    for (int i = 0; i < 4; i++){ bfg[i] = *reinterpret_cast<const bf16x8*>(Bp[i]); Bp[i] += 32; }
    #pragma unroll
    for (int i = 0; i < 4; i++)
      #pragma unroll
      for (int j = 0; j < 4; j++)
        acc[i][j] = __builtin_amdgcn_mfma_f32_16x16x32_bf16(af[i], bfg[j], acc[i][j], 0, 0, 0);
  }

  #pragma unroll
  for (int i = 0; i < 4; i++){
    #pragma unroll
    for (int j = 0; j < 4; j++){
      #pragma unroll
      for (int r = 0; r < 4; r++){
        int row = mBase + i*16 + q*4 + r;       // C/D layout: col=lane&15, row=quad*4+reg
        int col = nBase + j*16 + m15;
        float v = acc[i][j][r];
        if (mode == 0){
          outb[(long)row*ldo + col] = __float2bfloat16(v);
        } else if (mode == 1){
          outb[(long)(row >> 11)*8388608 + (long)(row & 2047)*1024 + woff + col] = __float2bfloat16(v);
        } else {
          resid[(long)row*1024 + col] += v;
        }
      }
    }
  }
}

// ---- GEGLU activation: U[8192][2688] -> E[8192][1344] ---------------------
__global__ __launch_bounds__(256) void k_act(const bf16* __restrict__ U, bf16* __restrict__ E){
  int idx = blockIdx.x*256 + threadIdx.x;        // < 8192*1344
  int row = idx / 1344;
  int j   = idx - row*1344;
  float g = (float)U[(long)row*2688 + j];
  float v = (float)U[(long)row*2688 + 1344 + j];
  float ge = 0.5f * g * (1.f + erff(g * 0.70710678118654752f));
  E[idx] = __float2bfloat16(ge * v);
}

// ---- sLSTM recurrence via M=4 MFMA, 8 waves, b-shared weights -------------
// grid = 4 (head h); 512 threads = 8 waves; launch_bounds(512,2) -> 256-reg
// unified budget/wave. Wave w owns n-tiles nt = w*8 + j8 (j8=0..7); fragment
// (kt, j8) maps onto R10's verified wbuf as (w' = 2w + (j8>>2), j' = j8&3):
// uint4 index = 32768h + 2048w' + 256kt + 64j' + lane. kt 0..4 register-
// resident (40 frags = 160 regs); kt 5..7 L2-streamed per step in 3 groups.
// A operand (hsr replicas), ylds 40B layout, update math, yout->WX: R10
// verbatim; update covers two b's per thread (b0 = tid>>8 and b0+2).
__global__ __launch_bounds__(512, 2) void k_recur(bf16* __restrict__ WX,        // [4b][4h][2048][1024]
                                                const uint4* __restrict__ wbufq,
                                                const void* __restrict__ cb, long cboff,
                                                const u32*  __restrict__ sig,
                                                int szero){
  int f32 = (sig[0] == SIGF32);
  int h = blockIdx.x;
  int tid = threadIdx.x;
  int lane = tid & 63, w = tid >> 6;
  int b0 = tid >> 8, cell = tid & 255;           // update: b0 and b0+2

  // fragment base pointers: w' = 2w (j8<4) and w' = 2w+1 (j8>=4)
  const uint4* wp0 = wbufq + 32768L*h + 4096L*w + lane;
  const uint4* wp1 = wp0 + 2048;

  // register-resident fragments kt = 0..4 (40 x f16x8 = 160 regs)
  f16x8 wfr[40];
  #pragma unroll
  for (int kt = 0; kt < 5; kt++)
    #pragma unroll
    for (int j8 = 0; j8 < 8; j8++)
      wfr[kt*8 + j8] = __builtin_bit_cast(f16x8,
          (j8 < 4 ? wp0 : wp1)[256*kt + 64*(j8 & 3)]);
  #pragma unroll
  for (int f = 0; f < 40; f++) asm volatile("" : "+v"(wfr[f]));

  __shared__ __align__(16) u16 hsr[4*272];        // 4 b-replicas, 544B stride (R10)
  __shared__ __align__(16) char ylds[1024*40];    // [n]: b f32 at n*40 + b*4 (R10)
  for (int i = tid; i < 544; i += 512) ((u32*)hsr)[i] = 0u;

  float bs0 = ldm(cb, cboff + h*1024 +   0 + cell, f32);
  float bs1 = ldm(cb, cboff + h*1024 + 256 + cell, f32);
  float bs2 = ldm(cb, cboff + h*1024 + 512 + cell, f32);
  float bs3 = ldm(cb, cboff + h*1024 + 768 + cell, f32);

  const u16* wxuA = (const u16*)WX + ((long)(b0*4 + h))*2097152 + cell;
  const u16* wxuB = (const u16*)WX + ((long)((b0+2)*4 + h))*2097152 + cell;
  u16* youtA = (u16*)WX + ((long)(b0*4 + h))*2097152 + cell;
  u16* youtB = (u16*)WX + ((long)((b0+2)*4 + h))*2097152 + cell;

  const char* hbase = (const char*)hsr + (lane & 3)*544 + ((lane >> 4) & 3)*16;
  char* ybase = ylds + ((long)w*128 + lane)*40;             // lanes<16 write
  const char* yrdA = ylds + (long)cell*40 + b0*4;
  const char* yrdB = yrdA + 8;                              // (b0+2)*4 - b0*4

  float c0s = 0.f, n0s = 0.f, m0s = 0.f;
  float c1s = 0.f, n1s = 0.f, m1s = 0.f;
  u16 xa0 = wxuA[0], xa1 = wxuA[256], xa2 = wxuA[512], xa3 = wxuA[768];
  u16 xb0 = wxuB[0], xb1 = wxuB[256], xb2 = wxuB[512], xb3 = wxuB[768];
  __syncthreads();

  for (int s = 0; s < 2048; s++){
    int off = s * szero;                         // runtime 0: defeats LICM
    int no = (s < 2047) ? 1024 : 0;              // next-row prefetch
    u16 pa0 = wxuA[no], pa1 = wxuA[no+256], pa2 = wxuA[no+512], pa3 = wxuA[no+768];
    u16 pb0 = wxuB[no], pb1 = wxuB[no+256], pb2 = wxuB[no+512], pb3 = wxuB[no+768];

    // streamed kt=5 issue
    uint4 sb[8];
    #pragma unroll
    for (int j8 = 0; j8 < 8; j8++)
      sb[j8] = (j8 < 4 ? wp0 : wp1)[256*5 + 64*(j8 & 3) + off];

    f32x4 acc[8];
    #pragma unroll
    for (int t = 0; t < 8; t++) acc[t] = (f32x4){0.f, 0.f, 0.f, 0.f};

    #pragma unroll
    for (int kt = 0; kt < 5; kt++){              // register-resident frags
      f16x8 af = *(const f16x8*)(hbase + kt*64 + off);
      #pragma unroll
      for (int j8 = 0; j8 < 8; j8++)
        acc[j8] = __builtin_amdgcn_mfma_f32_16x16x32_f16(af, wfr[kt*8 + j8], acc[j8], 0, 0, 0);
    }
    {                                            // kt=5 (streamed), issue kt=6
      f16x8 af = *(const f16x8*)(hbase + 5*64 + off);
      f16x8 bf[8];
      #pragma unroll
      for (int j8 = 0; j8 < 8; j8++) bf[j8] = __builtin_bit_cast(f16x8, sb[j8]);
      #pragma unroll
      for (int j8 = 0; j8 < 8; j8++)
        sb[j8] = (j8 < 4 ? wp0 : wp1)[256*6 + 64*(j8 & 3) + off];
      #pragma unroll
      for (int j8 = 0; j8 < 8; j8++)
        acc[j8] = __builtin_amdgcn_mfma_f32_16x16x32_f16(af, bf[j8], acc[j8], 0, 0, 0);
    }
    {                                            // kt=6, issue kt=7
      f16x8 af = *(const f16x8*)(hbase + 6*64 + off);
      f16x8 bf[8];
      #pragma unroll
      for (int j8 = 0; j8 < 8; j8++) bf[j8] = __builtin_bit_cast(f16x8, sb[j8]);
      #pragma unroll
      for (int j8 = 0; j8 < 8; j8++)
        sb[j8] = (j8 < 4 ? wp0 : wp1)[256*7 + 64*(j8 & 3) + off];
      #pragma unroll
      for (int j8 = 0; j8 < 8; j8++)
        acc[j8] = __builtin_amdgcn_mfma_f32_16x16x32_f16(af, bf[j8], acc[j8], 0, 0, 0);
    }
    {                                            // kt=7
      f16x8 af = *(const f16x8*)(hbase + 7*64 + off);
      #pragma unroll
      for (int j8 = 0; j8 < 8; j8++)
        acc[j8] = __builtin_amdgcn_mfma_f32_16x16x32_f16(af, __builtin_bit_cast(f16x8, sb[j8]), acc[j8], 0, 0, 0);
    }

    if (lane < 16){                              // C rows 0..3 = b (q=0 lanes)
      #pragma unroll
      for (int j8 = 0; j8 < 8; j8++){
        *(float2*)(ybase + j8*640 + 0 + off) = make_float2(acc[j8][0], acc[j8][1]);
        *(float2*)(ybase + j8*640 + 8)       = make_float2(acc[j8][2], acc[j8][3]);
      }
    }
    __syncthreads();                             // B1: ylds ready, hsr reads done

    // ---- update (b0, cell) — R10 verbatim ----
    {
      float a0 = *(const float*)(yrdA +     0 + off) + bs0 + bfu2f(xa0);
      float a1 = *(const float*)(yrdA + 10240)       + bs1 + bfu2f(xa1);
      float a2 = *(const float*)(yrdA + 20480)       + bs2 + bfu2f(xa2);
      float a3 = *(const float*)(yrdA + 30720)       + bs3 + bfu2f(xa3);
      float e1   = __expf(-fabsf(a1));
      float lsig = fminf(a1, 0.f) - __logf(1.f + e1);
      float lfm  = m0s + lsig;
      float mn   = fmaxf(a0, lfm);
      float ig   = __expf(a0 - mn);
      float fg   = __expf(lfm - mn);
      float t2   = __expf(-2.f*fabsf(a2));
      float th   = __builtin_copysignf(__fdividef(1.f - t2, 1.f + t2), a2);
      float cn   = fg*c0s + ig*th;
      float nn   = fg*n0s + ig;
      float sg   = __fdividef(1.f, 1.f + __expf(-a3));
      float hn   = sg * __fdividef(cn, nn);
      c0s = cn; n0s = nn; m0s = mn;
      u16 h16 = __builtin_bit_cast(u16, (_Float16)hn);
      hsr[b0*272 + cell] = h16;
      youtA[(long)s*1024] = h16;                 // f16 hn for deferred GN
    }
    // ---- update (b0+2, cell) ----
    {
      float a0 = *(const float*)(yrdB +     0) + bs0 + bfu2f(xb0);
      float a1 = *(const float*)(yrdB + 10240) + bs1 + bfu2f(xb1);
      float a2 = *(const float*)(yrdB + 20480) + bs2 + bfu2f(xb2);
      float a3 = *(const float*)(yrdB + 30720) + bs3 + bfu2f(xb3);
      float e1   = __expf(-fabsf(a1));
      float lsig = fminf(a1, 0.f) - __logf(1.f + e1);
      float lfm  = m1s + lsig;
      float mn   = fmaxf(a0, lfm);
      float ig   = __expf(a0 - mn);
      float fg   = __expf(lfm - mn);
      float t2   = __expf(-2.f*fabsf(a2));
      float th   = __builtin_copysignf(__fdividef(1.f - t2, 1.f + t2), a2);
      float cn   = fg*c1s + ig*th;
      float nn   = fg*n1s + ig;
      float sg   = __fdividef(1.f, 1.f + __expf(-a3));
      float hn   = sg * __fdividef(cn, nn);
      c1s = cn; n1s = nn; m1s = mn;
      u16 h16 = __builtin_bit_cast(u16, (_Float16)hn);
      hsr[(b0+2)*272 + cell] = h16;
      youtB[(long)s*1024] = h16;
    }
    __syncthreads();                             // B2: hsr(s+1) visible

    wxuA += 1024; wxuB += 1024;
    xa0 = pa0; xa1 = pa1; xa2 = pa2; xa3 = pa3;
    xb0 = pb0; xb1 = pb1; xb2 = pb2; xb3 = pb3;
  }
}

// ---- deferred GroupNorm + residual add: one block per (bh, s) row ---------
__global__ __launch_bounds__(256) void k_gn(const u16* __restrict__ Y,   // [16][2048][1024] rows, col<256 used
                                            const void* __restrict__ gnw, long gnoff,
                                            const u32* __restrict__ sig,
                                            float* __restrict__ X){
  int f32 = (sig[0] == SIGF32);
  int r = blockIdx.x;                 // < 32768
  int bh = r >> 11, s = r & 2047, b = bh >> 2, h = bh & 3;
  int t = threadIdx.x;                // cell
  float y = f16u2f(Y[(long)bh*2097152 + (long)s*1024 + t]);
  float s1 = y, s2 = y*y;
  #pragma unroll
  for (int off = 32; off >= 1; off >>= 1){ s1 += __shfl_xor(s1, off); s2 += __shfl_xor(s2, off); }
  __shared__ float rb[8];
  if ((t & 63) == 0){ rb[t>>6] = s1; rb[4 + (t>>6)] = s2; }
  __syncthreads();
  s1 = rb[0]+rb[1]+rb[2]+rb[3];
  s2 = rb[4]+rb[5]+rb[6]+rb[7];
  float mu  = s1 * (1.f/256.f);
  float var = s2 * (1.f/256.f) - mu*mu;
  float rs  = rsqrtf(fmaxf(var, 0.f) + EPSF);
  float gw  = ldm(gnw, gnoff + h*256 + t, f32);
  X[(long)b*2097152 + (long)s*1024 + h*256 + t] += (y - mu)*rs*gw;
}

// ---------------------------------------------------------------------------
extern "C" void kernel_launch(void* const* d_in, const int* in_sizes, int n_in,
                              void* d_out, int out_size, void* d_ws, size_t ws_size,
                              hipStream_t stream){
  const void* x_in   = d_in[0];
  const void* ln1_w  = d_in[1];
  const void* conv_w = d_in[2];
  const void* conv_b = d_in[3];
  const void* wi     = d_in[4];
  const void* wf     = d_in[5];
  const void* wz     = d_in[6];
  const void* wo     = d_in[7];
  const void* rker   = d_in[8];
  const void* cell_b = d_in[9];
  const void* gn_w   = d_in[10];
  const void* ln2_w  = d_in[11];
  const void* ff_up  = d_in[12];
  const void* ff_dn  = d_in[13];
  const void* post_w = d_in[14];
  const u32* sig = (const u32*)ln1_w;

  if (ws_size < 134217728ULL){
    k_canary<<<(out_size+255)/256, 256, 0, stream>>>(sig, d_out, out_size, 4000.f);
    return;
  }
  if (n_in < 15 || in_sizes[0] != 8388608 || in_sizes[8] != 4194304 ||
      in_sizes[12] != 11010048 || out_size != 8388608){
    k_canary<<<(out_size+255)/256, 256, 0, stream>>>(sig, d_out, out_size, 8000.f);
    return;
  }

  char* ws = (char*)d_ws;
  // layout (exactly 128 MiB):
  //   [0,32M)    X    fp32 residual
  //   [32,48M)   XN   bf16 LN output
  //   [48,64M)   scratch: wbuf 2M | gW 2M | fupT 5.25M | fdnT 2.63M
  //   [64,128M)  WX bf16 [4 b][4 h][2048 s][1024]; conv output lives in its
  //              z/o cols until side-1 gemms; recur's hn (f16) overwrites the
  //              dead gate-i cols; U(44M)+E(21M) alias it in FFN.
  float* X    = (float*)(ws + 0);
  bf16*  XN   = (bf16*) (ws + 33554432);
  u32*   wbuf = (u32*)  (ws + 50331648);
  bf16*  gW   = (bf16*) (ws + 50331648 + 2097152);
  bf16*  fupT = (bf16*) (ws + 50331648 + 4194304);
  bf16*  fdnT = (bf16*) (ws + 50331648 + 9699328);
  bf16*  WX   = (bf16*) (ws + 67108864);
  bf16*  U    = WX;
  bf16*  E    = (bf16*) (ws + 67108864 + 44040192);

  k_cast<<<8192, 256, 0, stream>>>(x_in, sig, X);

  for (int l = 0; l < 4; l++){
    k_ln<<<8192, 256, 0, stream>>>(X, ln1_w, (long)l*1024, sig, XN, 0);
    k_conv<<<32768, 256, 0, stream>>>(XN, conv_w, (long)l*4096, conv_b, (long)l*1024, sig, WX);

    // canonical bf16 gate weights for this layer
    k_cvt<<<1024, 256, 0, stream>>>(wi, (long)l*262144, sig, gW +      0, 262144);
    k_cvt<<<1024, 256, 0, stream>>>(wf, (long)l*262144, sig, gW + 262144, 262144);
    k_cvt<<<1024, 256, 0, stream>>>(wz, (long)l*262144, sig, gW + 524288, 262144);
    k_cvt<<<1024, 256, 0, stream>>>(wo, (long)l*262144, sig, gW + 786432, 262144);

    for (int h = 0; h < 4; h++){
      // gates i,f: A = conv output (in WX z/o cols), writes i/f cols
      k_gemm<<<dim3(64,4), 256, 0, stream>>>(WX, 0, h*2097152 + 512, 1,
          gW + h*65536, gW + 262144 + h*65536, 256, 256,
          256, 1, WX, 0, h*2097152 + 0, nullptr);
    }
    k_packrk<<<2048, 256, 0, stream>>>(rker, (long)l*1048576, sig, wbuf);
    for (int h = 0; h < 4; h++){
      // gates z,o: A = pre-conv XN, overwrites z/o cols (conv data now dead)
      k_gemm<<<dim3(64,4), 256, 0, stream>>>(XN, 1024, h*256, 0,
          gW + 524288 + h*65536, gW + 786432 + h*65536, 256, 256,
          256, 1, WX, 0, h*2097152 + 512, nullptr);
    }

    k_recur<<<4, 512, 0, stream>>>(WX, (const uint4*)wbuf,
                                   cell_b, (long)l*4096, sig, 0);
    k_gn<<<32768, 256, 0, stream>>>((const u16*)WX, gn_w, (long)l*1024, sig, X);

    k_ln<<<8192, 256, 0, stream>>>(X, ln2_w, (long)l*1024, sig, XN, 0);
    k_transpose<<<dim3(84,32), 256, 0, stream>>>(ff_up, (long)l*2752512, sig, fupT, 1024, 2688);
    k_gemm<<<dim3(64,21), 256, 0, stream>>>(XN, 1024, 0, 0, fupT, fupT, 1024, 1<<30,
        1024, 0, U, 2688, 0, nullptr);
    k_act<<<43008, 256, 0, stream>>>(U, E);
    k_transpose<<<dim3(32,42), 256, 0, stream>>>(ff_dn, (long)l*1376256, sig, fdnT, 1344, 1024);
    k_gemm<<<dim3(64,8), 256, 0, stream>>>(E, 1344, 0, 0, fdnT, fdnT, 1344, 1<<30,
        1344, 2, nullptr, 0, 0, X);
  }

  k_ln<<<8192, 256, 0, stream>>>(X, post_w, 0, sig, d_out, 1);
}